// Round 6
// baseline (278.816 us; speedup 1.0000x reference)
//
#include <hip/hip_runtime.h>
#include <hip/hip_bf16.h>

#define MODELS 64
#define BATCH 64
#define IN_DIM 512
#define UNITS 512
#define NCOLS 2048
// Packed-A: per tensor [m][ks16][kg4][row64] granules of 8 bf16 (16 B)
#define GRAN_PER_TENSOR (MODELS * 16 * 4 * 64)  // 262144 granules = 4 MB/tensor

typedef __attribute__((ext_vector_type(8))) short short8;
typedef __attribute__((ext_vector_type(4))) float f32x4;

static __device__ __forceinline__ short f2bf(float f) {
    return __builtin_bit_cast(short, __float2bfloat16(f));
}
static __device__ __forceinline__ float sigmoidf_(float x) {
    return 1.0f / (1.0f + __expf(-x));
}
static __device__ __forceinline__ float tanhf_(float x) {
    float e = __expf(-2.0f * fabsf(x));
    float r = (1.0f - e) / (1.0f + e);
    return copysignf(r, x);
}

// Re-layout inputs & h_tm1 (f32) into bf16 MFMA-A-fragment order.
__global__ __launch_bounds__(256) void prepack_A_kernel(
    const float* __restrict__ x, const float* __restrict__ h,
    short8* __restrict__ P)
{
    const int t = blockIdx.x * 256 + threadIdx.x;   // [0, 2*262144)
    const int tensor = t >> 18;
    const int r = t & (GRAN_PER_TENSOR - 1);
    const int kg = r & 3;
    const int row = (r >> 2) & 63;
    const int ks = (r >> 8) & 15;
    const int m = r >> 12;
    const float* src = (tensor ? h : x) + ((size_t)(m * 64 + row) * 512 + ks * 32 + kg * 8);
    f32x4 a0 = *(const f32x4*)src;
    f32x4 a1 = *(const f32x4*)(src + 4);
    short8 v;
    v[0] = f2bf(a0[0]); v[1] = f2bf(a0[1]); v[2] = f2bf(a0[2]); v[3] = f2bf(a0[3]);
    v[4] = f2bf(a1[0]); v[5] = f2bf(a1[1]); v[6] = f2bf(a1[2]); v[7] = f2bf(a1[3]);
    P[(size_t)tensor * GRAN_PER_TENSOR + (size_t)((m * 16 + ks) * 4 + kg) * 64 + row] = v;
}

// 1024 blocks x 256 threads, NO LDS, NO barriers. Wave = (model, 16 units, 32 batch).
// bid: half = bid>>9 (batch half), tile = bid&511 -> twins are 512 apart (same XCD).
// 2-set register pipeline: issue 34 loads for step t+1, vmcnt(34), compute step t.
__global__ __launch_bounds__(256, 3) void lstm_direct_kernel(
    const float* __restrict__ c_tm1,
    const float* __restrict__ kernel_,
    const float* __restrict__ rkernel,
    const float* __restrict__ bias,
    const short8* __restrict__ Pa,
    float* __restrict__ out)
{
    const int bid = blockIdx.x;
    const int half = bid >> 9;
    const int tile = bid & 511;
    const int m = tile >> 3;
    const int wave = threadIdx.x >> 6;
    const int lane = threadIdx.x & 63;
    const int col16 = lane & 15;
    const int kq = lane >> 4;
    const int ucol = (tile & 7) * 64 + wave * 16 + col16;  // unit column [0,512)
    const int brow0 = half * 32;                           // batch-row base

    const float* wbase[2] = { kernel_ + (size_t)m * IN_DIM * NCOLS,
                              rkernel + (size_t)m * UNITS * NCOLS };
    const short8* pabase[2] = { Pa + (size_t)m * 4096,
                                Pa + GRAN_PER_TENSOR + (size_t)m * 4096 };

    // B byte offset for (i, gate g): (kq*8+i)*8192 + g*2048 + ucol*4
    // centered: voffB[i] = (kq*8+i)*8192 + ucol*4 + 3072; imm(g) = g*2048 - 3072
    int voffB[8];
#pragma unroll
    for (int i = 0; i < 8; ++i) voffB[i] = (kq * 8 + i) * 8192 + ucol * 4 + 3072;
    // A granule byte offset: (kq*64 + brow0 + bt*16 + col16)*16; imm(bt) = bt*256
    const int voffA = (kq * 64 + brow0 + col16) * 16;

    f32x4 acc[2][4];
#pragma unroll
    for (int bt = 0; bt < 2; ++bt)
#pragma unroll
        for (int g = 0; g < 4; ++g) acc[bt][g] = (f32x4){0.f, 0.f, 0.f, 0.f};

    auto wptr = [&](int s) { return wbase[s >> 4] + (size_t)(s & 15) * 65536; };
    auto pptr = [&](int s) { return pabase[s >> 4] + (size_t)(s & 15) * 256; };

    auto ISSUE_B = [&](float (&B)[32], const float* wb) {
#pragma unroll
        for (int g = 0; g < 4; ++g)
#pragma unroll
            for (int i = 0; i < 8; ++i)
                asm volatile("global_load_dword %0, %1, %2 offset:%3"
                             : "=v"(B[g * 8 + i])
                             : "v"(voffB[i]), "s"(wb), "i"(g * 2048 - 3072)
                             : "memory");
    };
    auto ISSUE_A = [&](short8 (&A)[2], const short8* pp) {
        asm volatile("global_load_dwordx4 %0, %1, %2 offset:0"
                     : "=v"(A[0]) : "v"(voffA), "s"(pp) : "memory");
        asm volatile("global_load_dwordx4 %0, %1, %2 offset:256"
                     : "=v"(A[1]) : "v"(voffA), "s"(pp) : "memory");
    };
    auto COMPUTE = [&](float (&B)[32], short8 (&A)[2]) {
#pragma unroll
        for (int g = 0; g < 4; ++g) {
            short8 bfr;
#pragma unroll
            for (int i = 0; i < 8; ++i) bfr[i] = f2bf(B[g * 8 + i]);
            acc[0][g] = __builtin_amdgcn_mfma_f32_16x16x32_bf16(A[0], bfr, acc[0][g], 0, 0, 0);
            acc[1][g] = __builtin_amdgcn_mfma_f32_16x16x32_bf16(A[1], bfr, acc[1][g], 0, 0, 0);
        }
    };

    float Ba[32], Bb[32];
    short8 Aa[2], Ab[2];
    ISSUE_B(Ba, wptr(0));
    ISSUE_A(Aa, pptr(0));

    for (int sp = 0; sp < 16; ++sp) {
        const int se = 2 * sp;
        // issue step se+1, compute step se
        ISSUE_B(Bb, wptr(se + 1));
        ISSUE_A(Ab, pptr(se + 1));
        asm volatile("s_waitcnt vmcnt(34)" ::: "memory");
        __builtin_amdgcn_sched_barrier(0);
        COMPUTE(Ba, Aa);
        // issue step se+2, compute step se+1
        if (sp < 15) {
            ISSUE_B(Ba, wptr(se + 2));
            ISSUE_A(Aa, pptr(se + 2));
            asm volatile("s_waitcnt vmcnt(34)" ::: "memory");
        } else {
            asm volatile("s_waitcnt vmcnt(0)" ::: "memory");
        }
        __builtin_amdgcn_sched_barrier(0);
        COMPUTE(Bb, Ab);
    }

    // ---- fused gate epilogue, fully in-register ----
    const float* bp = bias + (size_t)m * NCOLS;
    const float bi = bp[0 * 512 + ucol];
    const float bff = bp[1 * 512 + ucol];
    const float bcc = bp[2 * 512 + ucol];
    const float bo = bp[3 * 512 + ucol];

    const size_t mbase = (size_t)m * (BATCH * UNITS);
    const float* cprev = c_tm1 + mbase;
    float* hout0 = out;
    float* hout1 = out + (size_t)MODELS * BATCH * UNITS;
    float* cout = out + 2 * (size_t)MODELS * BATCH * UNITS;

#pragma unroll
    for (int bt = 0; bt < 2; ++bt) {
#pragma unroll
        for (int r = 0; r < 4; ++r) {
            const int b = brow0 + bt * 16 + kq * 4 + r;   // batch row (D layout)
            const float z0 = acc[bt][0][r] + bi;
            const float z1 = acc[bt][1][r] + bff;
            const float z2 = acc[bt][2][r] + bcc;
            const float z3 = acc[bt][3][r] + bo;
            const float ig = sigmoidf_(z0);
            const float fg = sigmoidf_(z1);
            const float cand = tanhf_(z2);
            const float og = sigmoidf_(z3);
            const size_t idx = (size_t)b * UNITS + ucol;
            const float c = fg * cprev[idx] + ig * cand;
            const float hh = og * tanhf_(c);
            hout0[mbase + idx] = hh;
            hout1[mbase + idx] = hh;
            cout[mbase + idx] = c;
        }
    }
}

extern "C" void kernel_launch(void* const* d_in, const int* in_sizes, int n_in,
                              void* d_out, int out_size, void* d_ws, size_t ws_size,
                              hipStream_t stream) {
    const float* inputs = (const float*)d_in[0];
    const float* h_tm1 = (const float*)d_in[1];
    const float* c_tm1 = (const float*)d_in[2];
    const float* kernel_ = (const float*)d_in[3];
    const float* rkernel = (const float*)d_in[4];
    const float* bias = (const float*)d_in[5];
    float* out = (float*)d_out;

    short8* P = (short8*)d_ws;  // 8 MB of scratch
    hipLaunchKernelGGL(prepack_A_kernel, dim3(2 * GRAN_PER_TENSOR / 256), dim3(256),
                       0, stream, inputs, h_tm1, P);
    hipLaunchKernelGGL(lstm_direct_kernel, dim3(1024), dim3(256), 0, stream,
                       c_tm1, kernel_, rkernel, bias, P, out);
}

// Round 7
// 151.715 us; speedup vs baseline: 1.8378x; 1.8378x over previous
//
#include <hip/hip_runtime.h>
#include <hip/hip_bf16.h>

#define MODELS 64
#define BATCH 64
#define IN_DIM 512
#define UNITS 512
#define NCOLS 2048
// Packed-A: per tensor [m][ks16][kg4][row64] granules of 8 bf16 (16 B)
#define GRAN_PER_TENSOR (MODELS * 16 * 4 * 64)  // 262144 granules = 4 MB/tensor
#define ZSTRIDE 260  // z-exchange row stride (floats): 16B-aligned, conflict-free

typedef __attribute__((ext_vector_type(8))) short short8;
typedef __attribute__((ext_vector_type(4))) float f32x4;

static __device__ __forceinline__ short f2bf(float f) {
    return __builtin_bit_cast(short, __float2bfloat16(f));
}
static __device__ __forceinline__ float sigmoidf_(float x) {
    return 1.0f / (1.0f + __expf(-x));
}
static __device__ __forceinline__ float tanhf_(float x) {
    float e = __expf(-2.0f * fabsf(x));
    float r = (1.0f - e) / (1.0f + e);
    return copysignf(r, x);
}

// Re-layout inputs & h_tm1 (f32) into bf16 MFMA-A-fragment order.
__global__ __launch_bounds__(256) void prepack_A_kernel(
    const float* __restrict__ x, const float* __restrict__ h,
    short8* __restrict__ P)
{
    const int t = blockIdx.x * 256 + threadIdx.x;   // [0, 2*262144)
    const int tensor = t >> 18;
    const int r = t & (GRAN_PER_TENSOR - 1);
    const int kg = r & 3;
    const int row = (r >> 2) & 63;
    const int ks = (r >> 8) & 15;
    const int m = r >> 12;
    const float* src = (tensor ? h : x) + ((size_t)(m * 64 + row) * 512 + ks * 32 + kg * 8);
    f32x4 a0 = *(const f32x4*)src;
    f32x4 a1 = *(const f32x4*)(src + 4);
    short8 v;
    v[0] = f2bf(a0[0]); v[1] = f2bf(a0[1]); v[2] = f2bf(a0[2]); v[3] = f2bf(a0[3]);
    v[4] = f2bf(a1[0]); v[5] = f2bf(a1[1]); v[6] = f2bf(a1[2]); v[7] = f2bf(a1[3]);
    P[(size_t)tensor * GRAN_PER_TENSOR + (size_t)((m * 16 + ks) * 4 + kg) * 64 + row] = v;
}

// 512 blocks x 512 threads. NO in-loop barriers. Wave-private staging:
// wave = (gate g = wave>>1, unit-half uh = wave&1): B slice = 32k x 32cols (128 B/row).
// bid mapping: all 8 unit-tiles of a model land on ONE XCD (bid%8 = m%8), all co-resident.
__global__ __launch_bounds__(512, 4) void lstm_wave_kernel(
    const float* __restrict__ c_tm1,
    const float* __restrict__ kernel_,
    const float* __restrict__ rkernel,
    const float* __restrict__ bias,
    const short8* __restrict__ Pa,
    float* __restrict__ out)
{
    __shared__ float lds[16640];  // 65 KB: staging 8w*2buf*1024f; epilogue z[64][260]

    const int bid = blockIdx.x;
    const int slot = bid >> 3;
    const int m = ((slot >> 3) << 3) | (bid & 7);   // model (same XCD for all its tiles)
    const int u0 = (slot & 7) * 64;                 // unit tile base

    const int tid = threadIdx.x;
    const int wave = tid >> 6;
    const int lane = tid & 63;
    const int col16 = lane & 15;
    const int kq = lane >> 4;
    const int g = wave >> 1;                        // gate this wave owns
    const int uh = wave & 1;                        // unit half (32 cols)
    const int colf = g * 512 + u0 + uh * 32;        // first f32 col of wave's slice
    const int l3 = lane >> 3, l7 = lane & 7;

    const float* wbase[2] = { kernel_ + (size_t)m * IN_DIM * NCOLS,
                              rkernel + (size_t)m * UNITS * NCOLS };
    const short8* pabase[2] = { Pa + (size_t)m * 4096,
                                Pa + GRAN_PER_TENSOR + (size_t)m * 4096 };

    float* wlds = lds + wave * 2048;                // wave-private: 2 bufs x 1024 f32

    f32x4 acc[4][2];                                // [batch-tile][col-tile]
#pragma unroll
    for (int bt = 0; bt < 4; ++bt)
#pragma unroll
        for (int ct = 0; ct < 2; ++ct) acc[bt][ct] = (f32x4){0.f, 0.f, 0.f, 0.f};

    // Stage wave's [32k][32c] f32 slice. Source granule XOR-swizzled by row-group
    // (key j<<1, involution); LDS dest linear (base + lane*16).
    auto STAGE = [&](int step, int bufsel) {
        const char* wbc = (const char*)(wbase[step >> 4]
                          + (size_t)(step & 15) * 32 * NCOLS + colf);
#pragma unroll
        for (int j = 0; j < 4; ++j) {   // j = row-group = kq of rows j*8..j*8+7
            const char* src = wbc + l3 * 8192 + (((l7 << 4) ^ (j << 5))) + j * 65536;
            float* dst = wlds + bufsel * 1024 + j * 256;  // wave-uniform
            __builtin_amdgcn_global_load_lds(
                (const __attribute__((address_space(1))) void*)src,
                (__attribute__((address_space(3))) void*)dst, 16, 0, 0);
        }
    };
    auto LOADA = [&](int step, short8 (&af)[4]) {
        const short8* pb = pabase[step >> 4] + (size_t)((step & 15) * 4 + kq) * 64 + col16;
#pragma unroll
        for (int bt = 0; bt < 4; ++bt)
            asm volatile("global_load_dwordx4 %0, %1, off"
                         : "=v"(af[bt]) : "v"(pb + bt * 16) : "memory");
    };
    // Read B-fragment with matching inverse swizzle: granule (ct*4+q) ^ (kq<<1).
    auto COMPUTE = [&](int bufsel, short8 (&af)[4]) {
        const float* lb = wlds + bufsel * 1024;
#pragma unroll
        for (int ct = 0; ct < 2; ++ct) {
            const int gsw = (ct * 4 + (col16 >> 2)) ^ (kq << 1);
            const int base = kq * 256 + gsw * 4 + (col16 & 3);  // dword index
            short8 bfr;
#pragma unroll
            for (int i = 0; i < 8; ++i) bfr[i] = f2bf(lb[base + i * 32]);
#pragma unroll
            for (int bt = 0; bt < 4; ++bt)
                acc[bt][ct] = __builtin_amdgcn_mfma_f32_16x16x32_bf16(
                    af[bt], bfr, acc[bt][ct], 0, 0, 0);
        }
    };

    short8 afA[4], afB[4];
    STAGE(0, 0);
    LOADA(0, afA);

    for (int sp = 0; sp < 16; ++sp) {
        const int te = 2 * sp;
        // issue step te+1 (buf1/afB); compute step te (buf0/afA)
        STAGE(te + 1, 1);
        LOADA(te + 1, afB);
        asm volatile("s_waitcnt vmcnt(8)"   // drain stage_te + A_te (one full step old)
                     : "+v"(afA[0]), "+v"(afA[1]), "+v"(afA[2]), "+v"(afA[3]) :: "memory");
        __builtin_amdgcn_sched_barrier(0);
        COMPUTE(0, afA);
        __builtin_amdgcn_sched_barrier(0);
        // issue step te+2 (buf0/afA); compute step te+1 (buf1/afB)
        if (sp < 15) {
            STAGE(te + 2, 0);
            LOADA(te + 2, afA);
            asm volatile("s_waitcnt vmcnt(8)"
                         : "+v"(afB[0]), "+v"(afB[1]), "+v"(afB[2]), "+v"(afB[3]) :: "memory");
        } else {
            asm volatile("s_waitcnt vmcnt(0)"
                         : "+v"(afB[0]), "+v"(afB[1]), "+v"(afB[2]), "+v"(afB[3]) :: "memory");
        }
        __builtin_amdgcn_sched_barrier(0);
        COMPUTE(1, afB);
        __builtin_amdgcn_sched_barrier(0);
    }

    // ---- z exchange (only barriers in the kernel) ----
    __syncthreads();   // everyone done with staging buffers
#pragma unroll
    for (int bt = 0; bt < 4; ++bt)
#pragma unroll
        for (int ct = 0; ct < 2; ++ct)
#pragma unroll
            for (int r = 0; r < 4; ++r)
                lds[(size_t)(bt * 16 + kq * 4 + r) * ZSTRIDE
                    + g * 64 + uh * 32 + ct * 16 + col16] = acc[bt][ct][r];
    __syncthreads();

    // ---- fused gate epilogue: thread -> (batch b, 8 units) ----
    const int b = tid >> 3;
    const int ug = (tid & 7) * 8;
    const float* zrow = lds + (size_t)b * ZSTRIDE;

    float zi[8], zf[8], zc[8], zo[8];
    *(f32x4*)&zi[0] = *(const f32x4*)&zrow[0 + ug];
    *(f32x4*)&zi[4] = *(const f32x4*)&zrow[0 + ug + 4];
    *(f32x4*)&zf[0] = *(const f32x4*)&zrow[64 + ug];
    *(f32x4*)&zf[4] = *(const f32x4*)&zrow[64 + ug + 4];
    *(f32x4*)&zc[0] = *(const f32x4*)&zrow[128 + ug];
    *(f32x4*)&zc[4] = *(const f32x4*)&zrow[128 + ug + 4];
    *(f32x4*)&zo[0] = *(const f32x4*)&zrow[192 + ug];
    *(f32x4*)&zo[4] = *(const f32x4*)&zrow[192 + ug + 4];

    const float* bb = bias + (size_t)m * NCOLS;
    float bi[8], bf_[8], bc[8], bo[8];
    *(f32x4*)&bi[0] = *(const f32x4*)&bb[0 * 512 + u0 + ug];
    *(f32x4*)&bi[4] = *(const f32x4*)&bb[0 * 512 + u0 + ug + 4];
    *(f32x4*)&bf_[0] = *(const f32x4*)&bb[1 * 512 + u0 + ug];
    *(f32x4*)&bf_[4] = *(const f32x4*)&bb[1 * 512 + u0 + ug + 4];
    *(f32x4*)&bc[0] = *(const f32x4*)&bb[2 * 512 + u0 + ug];
    *(f32x4*)&bc[4] = *(const f32x4*)&bb[2 * 512 + u0 + ug + 4];
    *(f32x4*)&bo[0] = *(const f32x4*)&bb[3 * 512 + u0 + ug];
    *(f32x4*)&bo[4] = *(const f32x4*)&bb[3 * 512 + u0 + ug + 4];

    const size_t cidx = (size_t)m * (BATCH * UNITS) + (size_t)b * UNITS + u0 + ug;
    float cp[8];
    *(f32x4*)&cp[0] = *(const f32x4*)&c_tm1[cidx];
    *(f32x4*)&cp[4] = *(const f32x4*)&c_tm1[cidx + 4];

    float hv[8], cv[8];
#pragma unroll
    for (int j = 0; j < 8; ++j) {
        const float ig = sigmoidf_(zi[j] + bi[j]);
        const float fg = sigmoidf_(zf[j] + bf_[j]);
        const float cand = tanhf_(zc[j] + bc[j]);
        const float og = sigmoidf_(zo[j] + bo[j]);
        const float c = fg * cp[j] + ig * cand;
        cv[j] = c;
        hv[j] = og * tanhf_(c);
    }

    float* hout0 = out;
    float* hout1 = out + (size_t)MODELS * BATCH * UNITS;
    float* cout = out + 2 * (size_t)MODELS * BATCH * UNITS;
    *(f32x4*)&hout0[cidx] = *(const f32x4*)&hv[0];
    *(f32x4*)&hout0[cidx + 4] = *(const f32x4*)&hv[4];
    *(f32x4*)&hout1[cidx] = *(const f32x4*)&hv[0];
    *(f32x4*)&hout1[cidx + 4] = *(const f32x4*)&hv[4];
    *(f32x4*)&cout[cidx] = *(const f32x4*)&cv[0];
    *(f32x4*)&cout[cidx + 4] = *(const f32x4*)&cv[4];
}

extern "C" void kernel_launch(void* const* d_in, const int* in_sizes, int n_in,
                              void* d_out, int out_size, void* d_ws, size_t ws_size,
                              hipStream_t stream) {
    const float* inputs = (const float*)d_in[0];
    const float* h_tm1 = (const float*)d_in[1];
    const float* c_tm1 = (const float*)d_in[2];
    const float* kernel_ = (const float*)d_in[3];
    const float* rkernel = (const float*)d_in[4];
    const float* bias = (const float*)d_in[5];
    float* out = (float*)d_out;

    short8* P = (short8*)d_ws;  // 8 MB of scratch
    hipLaunchKernelGGL(prepack_A_kernel, dim3(2 * GRAN_PER_TENSOR / 256), dim3(256),
                       0, stream, inputs, h_tm1, P);
    hipLaunchKernelGGL(lstm_wave_kernel, dim3(512), dim3(512), 0, stream,
                       c_tm1, kernel_, rkernel, bias, P, out);
}

// Round 8
// 142.685 us; speedup vs baseline: 1.9541x; 1.0633x over previous
//
#include <hip/hip_runtime.h>
#include <hip/hip_bf16.h>

#define MODELS 64
#define BATCH 64
#define IN_DIM 512
#define UNITS 512
#define NCOLS 2048
// Packed-A: per tensor [m][ks16][kg4][row64] granules of 8 bf16 (16 B)
#define GRAN_PER_TENSOR (MODELS * 16 * 4 * 64)  // 262144 granules = 4 MB/tensor
#define ZS 130  // z-exchange row stride (f32): bank-spread, 2-way max

typedef __attribute__((ext_vector_type(8))) short short8;
typedef __attribute__((ext_vector_type(4))) float f32x4;

static __device__ __forceinline__ short f2bf(float f) {
    return __builtin_bit_cast(short, __float2bfloat16(f));
}
static __device__ __forceinline__ float sigmoidf_(float x) {
    return 1.0f / (1.0f + __expf(-x));
}
static __device__ __forceinline__ float tanhf_(float x) {
    float e = __expf(-2.0f * fabsf(x));
    float r = (1.0f - e) / (1.0f + e);
    return copysignf(r, x);
}

// Re-layout inputs & h_tm1 (f32) into bf16 MFMA-A-fragment order.
__global__ __launch_bounds__(256) void prepack_A_kernel(
    const float* __restrict__ x, const float* __restrict__ h,
    short8* __restrict__ P)
{
    const int t = blockIdx.x * 256 + threadIdx.x;   // [0, 2*262144)
    const int tensor = t >> 18;
    const int r = t & (GRAN_PER_TENSOR - 1);
    const int kg = r & 3;
    const int row = (r >> 2) & 63;
    const int ks = (r >> 8) & 15;
    const int m = r >> 12;
    const float* src = (tensor ? h : x) + ((size_t)(m * 64 + row) * 512 + ks * 32 + kg * 8);
    f32x4 a0 = *(const f32x4*)src;
    f32x4 a1 = *(const f32x4*)(src + 4);
    short8 v;
    v[0] = f2bf(a0[0]); v[1] = f2bf(a0[1]); v[2] = f2bf(a0[2]); v[3] = f2bf(a0[3]);
    v[4] = f2bf(a1[0]); v[5] = f2bf(a1[1]); v[6] = f2bf(a1[2]); v[7] = f2bf(a1[3]);
    P[(size_t)tensor * GRAN_PER_TENSOR + (size_t)((m * 16 + ks) * 4 + kg) * 64 + row] = v;
}

// 1024 blocks (model x 16 tiles of 32 units) x 256 threads (4 waves), 4 blocks/CU.
// Per block: stage [32k][128 packed cols] f32 double-buffered (32 KB), XOR-swizzled
// (key = (row>>3)<<3, pre-swizzled source + matching read). acc[4 bt][2 ct] per wave.
__global__ __launch_bounds__(256, 4) void lstm_main_kernel(
    const float* __restrict__ c_tm1,
    const float* __restrict__ kernel_,
    const float* __restrict__ rkernel,
    const float* __restrict__ bias,
    const short8* __restrict__ Pa,
    float* __restrict__ out)
{
    __shared__ float lds[8320];  // 33.3 KB: stage 2x4096 f32; epilogue z[64][130]

    const int bid = blockIdx.x;
    const int m = bid >> 4;
    const int u0 = (bid & 15) * 32;

    const int tid = threadIdx.x;
    const int w = tid >> 6;          // wave 0..3
    const int lane = tid & 63;
    const int col16 = lane & 15;
    const int kq = lane >> 4;

    const float* wbase[2] = { kernel_ + (size_t)m * IN_DIM * NCOLS,
                              rkernel + (size_t)m * UNITS * NCOLS };
    const short8* pabase[2] = { Pa + (size_t)m * 4096,
                                Pa + GRAN_PER_TENSOR + (size_t)m * 4096 };

    // per-thread stage source offsets (f32) for j = 0..3:
    // row r = 8j + 2w + (lane>>5); swizzled pos p = (lane&31)*4, true pc = p ^ (j<<3)
    int soff[4];
#pragma unroll
    for (int j = 0; j < 4; ++j) {
        const int r = 8 * j + 2 * w + (lane >> 5);
        const int pc = ((lane & 31) * 4) ^ (j << 3);
        soff[j] = r * NCOLS + (pc >> 5) * 512 + u0 + (pc & 31);
    }

    f32x4 acc[4][2];
#pragma unroll
    for (int bt = 0; bt < 4; ++bt)
#pragma unroll
        for (int ct = 0; ct < 2; ++ct) acc[bt][ct] = (f32x4){0.f, 0.f, 0.f, 0.f};

    auto STAGE = [&](int step, int bufsel) {
        const float* wb = wbase[step >> 4] + (size_t)(step & 15) * 32 * NCOLS;
#pragma unroll
        for (int j = 0; j < 4; ++j) {
            const float* src = wb + soff[j];
            float* dst = lds + bufsel * 4096 + (j * 4 + w) * 256;  // wave-uniform
            __builtin_amdgcn_global_load_lds(
                (const __attribute__((address_space(1))) void*)src,
                (__attribute__((address_space(3))) void*)dst, 16, 0, 0);
        }
    };
    auto LOADA = [&](int step, short8 (&af)[4]) {
        const short8* pb = pabase[step >> 4] + (size_t)((step & 15) * 4 + kq) * 64 + col16;
#pragma unroll
        for (int bt = 0; bt < 4; ++bt)
            asm volatile("global_load_dwordx4 %0, %1, off"
                         : "=v"(af[bt]) : "v"(pb + bt * 16) : "memory");
    };
    // read with matching swizzle: pos = pc ^ (kq<<3), rows kq*8..+7
    auto COMPUTE = [&](int bufsel, short8 (&af)[4]) {
        const float* lb = lds + bufsel * 4096;
#pragma unroll
        for (int ct = 0; ct < 2; ++ct) {
            const int pc = w * 32 + ct * 16 + col16;
            const int rd = kq * 1024 + (pc ^ (kq << 3));
            short8 bfr;
#pragma unroll
            for (int i = 0; i < 8; ++i) bfr[i] = f2bf(lb[rd + i * 128]);
#pragma unroll
            for (int bt = 0; bt < 4; ++bt)
                acc[bt][ct] = __builtin_amdgcn_mfma_f32_16x16x32_bf16(
                    af[bt], bfr, acc[bt][ct], 0, 0, 0);
        }
    };

    short8 afA[4], afB[4];
    STAGE(0, 0);
    LOADA(0, afA);

    for (int sp = 0; sp < 16; ++sp) {
        const int te = 2 * sp;
        STAGE(te + 1, 1);
        LOADA(te + 1, afB);
        asm volatile("s_waitcnt vmcnt(8)"   // drain stage_te + A_te (one full step old)
                     : "+v"(afA[0]), "+v"(afA[1]), "+v"(afA[2]), "+v"(afA[3]) :: "memory");
        asm volatile("s_barrier" ::: "memory");
        COMPUTE(0, afA);
        asm volatile("s_waitcnt lgkmcnt(0)" ::: "memory");
        asm volatile("s_barrier" ::: "memory");
        if (sp < 15) {
            STAGE(te + 2, 0);
            LOADA(te + 2, afA);
            asm volatile("s_waitcnt vmcnt(8)"
                         : "+v"(afB[0]), "+v"(afB[1]), "+v"(afB[2]), "+v"(afB[3]) :: "memory");
        } else {
            asm volatile("s_waitcnt vmcnt(0)"
                         : "+v"(afB[0]), "+v"(afB[1]), "+v"(afB[2]), "+v"(afB[3]) :: "memory");
        }
        asm volatile("s_barrier" ::: "memory");
        COMPUTE(1, afB);
        asm volatile("s_waitcnt lgkmcnt(0)" ::: "memory");
        asm volatile("s_barrier" ::: "memory");
    }

    // ---- z exchange: z[64 batch][130] over packed cols 0..127 ----
    __syncthreads();
#pragma unroll
    for (int bt = 0; bt < 4; ++bt)
#pragma unroll
        for (int ct = 0; ct < 2; ++ct) {
            const int pc = w * 32 + ct * 16 + col16;
#pragma unroll
            for (int r = 0; r < 4; ++r)
                lds[(size_t)(bt * 16 + kq * 4 + r) * ZS + pc] = acc[bt][ct][r];
        }
    __syncthreads();

    // ---- fused gate epilogue: thread -> (batch b = tid>>2, 8 units) ----
    const int b = tid >> 2;
    const int ug = (tid & 3) * 8;                 // unit offset within the 32-unit tile
    const float* zrow = lds + (size_t)b * ZS;

    float zi[8], zf[8], zc[8], zo[8];
    *(f32x4*)&zi[0] = *(const f32x4*)&zrow[0 + ug];
    *(f32x4*)&zi[4] = *(const f32x4*)&zrow[0 + ug + 4];
    *(f32x4*)&zf[0] = *(const f32x4*)&zrow[32 + ug];
    *(f32x4*)&zf[4] = *(const f32x4*)&zrow[32 + ug + 4];
    *(f32x4*)&zc[0] = *(const f32x4*)&zrow[64 + ug];
    *(f32x4*)&zc[4] = *(const f32x4*)&zrow[64 + ug + 4];
    *(f32x4*)&zo[0] = *(const f32x4*)&zrow[96 + ug];
    *(f32x4*)&zo[4] = *(const f32x4*)&zrow[96 + ug + 4];

    const float* bb = bias + (size_t)m * NCOLS + u0 + ug;
    float bi[8], bf_[8], bc[8], bo[8];
    *(f32x4*)&bi[0] = *(const f32x4*)&bb[0];
    *(f32x4*)&bi[4] = *(const f32x4*)&bb[4];
    *(f32x4*)&bf_[0] = *(const f32x4*)&bb[512];
    *(f32x4*)&bf_[4] = *(const f32x4*)&bb[512 + 4];
    *(f32x4*)&bc[0] = *(const f32x4*)&bb[1024];
    *(f32x4*)&bc[4] = *(const f32x4*)&bb[1024 + 4];
    *(f32x4*)&bo[0] = *(const f32x4*)&bb[1536];
    *(f32x4*)&bo[4] = *(const f32x4*)&bb[1536 + 4];

    const size_t cidx = (size_t)m * (BATCH * UNITS) + (size_t)b * UNITS + u0 + ug;
    float cp[8];
    *(f32x4*)&cp[0] = *(const f32x4*)&c_tm1[cidx];
    *(f32x4*)&cp[4] = *(const f32x4*)&c_tm1[cidx + 4];

    float hv[8], cv[8];
#pragma unroll
    for (int j = 0; j < 8; ++j) {
        const float ig = sigmoidf_(zi[j] + bi[j]);
        const float fg = sigmoidf_(zf[j] + bf_[j]);
        const float cand = tanhf_(zc[j] + bc[j]);
        const float og = sigmoidf_(zo[j] + bo[j]);
        const float c = fg * cp[j] + ig * cand;
        cv[j] = c;
        hv[j] = og * tanhf_(c);
    }

    float* hout0 = out;
    float* hout1 = out + (size_t)MODELS * BATCH * UNITS;
    float* cout = out + 2 * (size_t)MODELS * BATCH * UNITS;
    *(f32x4*)&hout0[cidx] = *(const f32x4*)&hv[0];
    *(f32x4*)&hout0[cidx + 4] = *(const f32x4*)&hv[4];
    *(f32x4*)&hout1[cidx] = *(const f32x4*)&hv[0];
    *(f32x4*)&hout1[cidx + 4] = *(const f32x4*)&hv[4];
    *(f32x4*)&cout[cidx] = *(const f32x4*)&cv[0];
    *(f32x4*)&cout[cidx + 4] = *(const f32x4*)&cv[4];
}

extern "C" void kernel_launch(void* const* d_in, const int* in_sizes, int n_in,
                              void* d_out, int out_size, void* d_ws, size_t ws_size,
                              hipStream_t stream) {
    const float* inputs = (const float*)d_in[0];
    const float* h_tm1 = (const float*)d_in[1];
    const float* c_tm1 = (const float*)d_in[2];
    const float* kernel_ = (const float*)d_in[3];
    const float* rkernel = (const float*)d_in[4];
    const float* bias = (const float*)d_in[5];
    float* out = (float*)d_out;

    short8* P = (short8*)d_ws;  // 8 MB of scratch
    hipLaunchKernelGGL(prepack_A_kernel, dim3(2 * GRAN_PER_TENSOR / 256), dim3(256),
                       0, stream, inputs, h_tm1, P);
    hipLaunchKernelGGL(lstm_main_kernel, dim3(MODELS * 16), dim3(256), 0, stream,
                       c_tm1, kernel_, rkernel, bias, P, out);
}

// Round 9
// 142.373 us; speedup vs baseline: 1.9583x; 1.0022x over previous
//
#include <hip/hip_runtime.h>
#include <hip/hip_bf16.h>

#define MODELS 64
#define BATCH 64
#define IN_DIM 512
#define UNITS 512
#define NCOLS 2048
// Packed-A: per tensor [m][ks16][kg4][row64] granules of 8 bf16 (16 B)
#define GRAN_PER_TENSOR (MODELS * 16 * 4 * 64)  // 262144 granules = 4 MB/tensor
#define ZS 130  // z-exchange row stride (f32)

typedef __attribute__((ext_vector_type(8))) short short8;
typedef __attribute__((ext_vector_type(4))) float f32x4;

static __device__ __forceinline__ short f2bf(float f) {
    return __builtin_bit_cast(short, __float2bfloat16(f));
}
static __device__ __forceinline__ float sigmoidf_(float x) {
    return 1.0f / (1.0f + __expf(-x));
}
static __device__ __forceinline__ float tanhf_(float x) {
    float e = __expf(-2.0f * fabsf(x));
    float r = (1.0f - e) / (1.0f + e);
    return copysignf(r, x);
}

// Re-layout inputs & h_tm1 (f32) into bf16 MFMA-A-fragment order.
__global__ __launch_bounds__(256) void prepack_A_kernel(
    const float* __restrict__ x, const float* __restrict__ h,
    short8* __restrict__ P)
{
    const int t = blockIdx.x * 256 + threadIdx.x;   // [0, 2*262144)
    const int tensor = t >> 18;
    const int r = t & (GRAN_PER_TENSOR - 1);
    const int kg = r & 3;
    const int row = (r >> 2) & 63;
    const int ks = (r >> 8) & 15;
    const int m = r >> 12;
    const float* src = (tensor ? h : x) + ((size_t)(m * 64 + row) * 512 + ks * 32 + kg * 8);
    f32x4 a0 = *(const f32x4*)src;
    f32x4 a1 = *(const f32x4*)(src + 4);
    short8 v;
    v[0] = f2bf(a0[0]); v[1] = f2bf(a0[1]); v[2] = f2bf(a0[2]); v[3] = f2bf(a0[3]);
    v[4] = f2bf(a1[0]); v[5] = f2bf(a1[1]); v[6] = f2bf(a1[2]); v[7] = f2bf(a1[3]);
    P[(size_t)tensor * GRAN_PER_TENSOR + (size_t)((m * 16 + ks) * 4 + kg) * 64 + row] = v;
}

// 1024 blocks (model x 16 tiles of 32 units) x 256 threads (4 waves), 3 blocks/CU.
// TRIPLE-buffered stage [32k][128 packed cols] f32, 2-step lookahead:
// steady-state s_waitcnt vmcnt(16) drains loads issued two full steps earlier.
__global__ __launch_bounds__(256, 3) void lstm_main_kernel(
    const float* __restrict__ c_tm1,
    const float* __restrict__ kernel_,
    const float* __restrict__ rkernel,
    const float* __restrict__ bias,
    const short8* __restrict__ Pa,
    float* __restrict__ out)
{
    __shared__ float lds[12288];  // 48 KB: 3 stage bufs x 4096 f32; z[64][130] overlays

    const int bid = blockIdx.x;
    const int m = bid >> 4;
    const int u0 = (bid & 15) * 32;

    const int tid = threadIdx.x;
    const int w = tid >> 6;          // wave 0..3
    const int lane = tid & 63;
    const int col16 = lane & 15;
    const int kq = lane >> 4;

    const float* wbase[2] = { kernel_ + (size_t)m * IN_DIM * NCOLS,
                              rkernel + (size_t)m * UNITS * NCOLS };
    const short8* pabase[2] = { Pa + (size_t)m * 4096,
                                Pa + GRAN_PER_TENSOR + (size_t)m * 4096 };

    // per-thread stage source offsets (f32), XOR-swizzled (key (row>>3)<<3):
    int soff[4];
#pragma unroll
    for (int j = 0; j < 4; ++j) {
        const int r = 8 * j + 2 * w + (lane >> 5);
        const int pc = ((lane & 31) * 4) ^ (j << 3);
        soff[j] = r * NCOLS + (pc >> 5) * 512 + u0 + (pc & 31);
    }

    f32x4 acc[4][2];
#pragma unroll
    for (int bt = 0; bt < 4; ++bt)
#pragma unroll
        for (int ct = 0; ct < 2; ++ct) acc[bt][ct] = (f32x4){0.f, 0.f, 0.f, 0.f};

    auto STAGE = [&](int step, int bufsel) {
        const float* wb = wbase[step >> 4] + (size_t)(step & 15) * 32 * NCOLS;
#pragma unroll
        for (int j = 0; j < 4; ++j) {
            const float* src = wb + soff[j];
            float* dst = lds + bufsel * 4096 + (j * 4 + w) * 256;  // wave-uniform
            __builtin_amdgcn_global_load_lds(
                (const __attribute__((address_space(1))) void*)src,
                (__attribute__((address_space(3))) void*)dst, 16, 0, 0);
        }
    };
    auto LOADA = [&](int step, short8 (&af)[4]) {
        const short8* pb = pabase[step >> 4] + (size_t)((step & 15) * 4 + kq) * 64 + col16;
#pragma unroll
        for (int bt = 0; bt < 4; ++bt)
            asm volatile("global_load_dwordx4 %0, %1, off"
                         : "=v"(af[bt]) : "v"(pb + bt * 16) : "memory");
    };
    auto COMPUTE = [&](int bufsel, short8 (&af)[4]) {
        const float* lb = lds + bufsel * 4096;
#pragma unroll
        for (int ct = 0; ct < 2; ++ct) {
            const int pc = w * 32 + ct * 16 + col16;
            const int rd = kq * 1024 + (pc ^ (kq << 3));
            short8 bfr;
#pragma unroll
            for (int i = 0; i < 8; ++i) bfr[i] = f2bf(lb[rd + i * 128]);
#pragma unroll
            for (int bt = 0; bt < 4; ++bt)
                acc[bt][ct] = __builtin_amdgcn_mfma_f32_16x16x32_bf16(
                    af[bt], bfr, acc[bt][ct], 0, 0, 0);
        }
    };

#define WAITV(N, af)                                                         \
    asm volatile("s_waitcnt vmcnt(" #N ")"                                   \
                 : "+v"(af[0]), "+v"(af[1]), "+v"(af[2]), "+v"(af[3])        \
                 :: "memory")
#define BAR() asm volatile("s_barrier" ::: "memory")
#define LGKM0() asm volatile("s_waitcnt lgkmcnt(0)" ::: "memory")

    short8 afA[4], afB[4], afC[4];
    // prologue: steps 0,1 in flight
    STAGE(0, 0); LOADA(0, afA);
    STAGE(1, 1); LOADA(1, afB);

    // steps 0..29 in 3-unrolled blocks; prefetch depth 2 throughout
    for (int tb = 0; tb < 30; tb += 3) {
        // step tb: prefetch tb+2 -> buf2/afC; compute buf0/afA
        STAGE(tb + 2, 2); LOADA(tb + 2, afC);
        WAITV(16, afA); BAR();
        COMPUTE(0, afA);
        LGKM0(); BAR();
        // step tb+1: prefetch tb+3 -> buf0/afA; compute buf1/afB
        STAGE(tb + 3, 0); LOADA(tb + 3, afA);
        WAITV(16, afB); BAR();
        COMPUTE(1, afB);
        LGKM0(); BAR();
        // step tb+2: prefetch tb+4 -> buf1/afB; compute buf2/afC
        STAGE(tb + 4, 1); LOADA(tb + 4, afB);
        WAITV(16, afC); BAR();
        COMPUTE(2, afC);
        LGKM0(); BAR();
    }
    // step 30: outstanding {30,31} -> drain 30
    WAITV(8, afA); BAR();
    COMPUTE(0, afA);
    LGKM0(); BAR();
    // step 31
    WAITV(0, afB); BAR();
    COMPUTE(1, afB);

    // ---- z exchange: z[64 batch][130] over packed cols 0..127 ----
    __syncthreads();
#pragma unroll
    for (int bt = 0; bt < 4; ++bt)
#pragma unroll
        for (int ct = 0; ct < 2; ++ct) {
            const int pc = w * 32 + ct * 16 + col16;
#pragma unroll
            for (int r = 0; r < 4; ++r)
                lds[(size_t)(bt * 16 + kq * 4 + r) * ZS + pc] = acc[bt][ct][r];
        }
    __syncthreads();

    // ---- fused gate epilogue: thread -> (batch b = tid>>2, 8 units) ----
    const int b = tid >> 2;
    const int ug = (tid & 3) * 8;
    const float* zrow = lds + (size_t)b * ZS;

    float zi[8], zf[8], zc[8], zo[8];
    *(f32x4*)&zi[0] = *(const f32x4*)&zrow[0 + ug];
    *(f32x4*)&zi[4] = *(const f32x4*)&zrow[0 + ug + 4];
    *(f32x4*)&zf[0] = *(const f32x4*)&zrow[32 + ug];
    *(f32x4*)&zf[4] = *(const f32x4*)&zrow[32 + ug + 4];
    *(f32x4*)&zc[0] = *(const f32x4*)&zrow[64 + ug];
    *(f32x4*)&zc[4] = *(const f32x4*)&zrow[64 + ug + 4];
    *(f32x4*)&zo[0] = *(const f32x4*)&zrow[96 + ug];
    *(f32x4*)&zo[4] = *(const f32x4*)&zrow[96 + ug + 4];

    const float* bb = bias + (size_t)m * NCOLS + u0 + ug;
    float bi[8], bf_[8], bc[8], bo[8];
    *(f32x4*)&bi[0] = *(const f32x4*)&bb[0];
    *(f32x4*)&bi[4] = *(const f32x4*)&bb[4];
    *(f32x4*)&bf_[0] = *(const f32x4*)&bb[512];
    *(f32x4*)&bf_[4] = *(const f32x4*)&bb[512 + 4];
    *(f32x4*)&bc[0] = *(const f32x4*)&bb[1024];
    *(f32x4*)&bc[4] = *(const f32x4*)&bb[1024 + 4];
    *(f32x4*)&bo[0] = *(const f32x4*)&bb[1536];
    *(f32x4*)&bo[4] = *(const f32x4*)&bb[1536 + 4];

    const size_t cidx = (size_t)m * (BATCH * UNITS) + (size_t)b * UNITS + u0 + ug;
    float cp[8];
    *(f32x4*)&cp[0] = *(const f32x4*)&c_tm1[cidx];
    *(f32x4*)&cp[4] = *(const f32x4*)&c_tm1[cidx + 4];

    float hv[8], cv[8];
#pragma unroll
    for (int j = 0; j < 8; ++j) {
        const float ig = sigmoidf_(zi[j] + bi[j]);
        const float fg = sigmoidf_(zf[j] + bf_[j]);
        const float cand = tanhf_(zc[j] + bc[j]);
        const float og = sigmoidf_(zo[j] + bo[j]);
        const float c = fg * cp[j] + ig * cand;
        cv[j] = c;
        hv[j] = og * tanhf_(c);
    }

    float* hout0 = out;
    float* hout1 = out + (size_t)MODELS * BATCH * UNITS;
    float* cout = out + 2 * (size_t)MODELS * BATCH * UNITS;
    *(f32x4*)&hout0[cidx] = *(const f32x4*)&hv[0];
    *(f32x4*)&hout0[cidx + 4] = *(const f32x4*)&hv[4];
    *(f32x4*)&hout1[cidx] = *(const f32x4*)&hv[0];
    *(f32x4*)&hout1[cidx + 4] = *(const f32x4*)&hv[4];
    *(f32x4*)&cout[cidx] = *(const f32x4*)&cv[0];
    *(f32x4*)&cout[cidx + 4] = *(const f32x4*)&cv[4];
}

extern "C" void kernel_launch(void* const* d_in, const int* in_sizes, int n_in,
                              void* d_out, int out_size, void* d_ws, size_t ws_size,
                              hipStream_t stream) {
    const float* inputs = (const float*)d_in[0];
    const float* h_tm1 = (const float*)d_in[1];
    const float* c_tm1 = (const float*)d_in[2];
    const float* kernel_ = (const float*)d_in[3];
    const float* rkernel = (const float*)d_in[4];
    const float* bias = (const float*)d_in[5];
    float* out = (float*)d_out;

    short8* P = (short8*)d_ws;  // 8 MB of scratch
    hipLaunchKernelGGL(prepack_A_kernel, dim3(2 * GRAN_PER_TENSOR / 256), dim3(256),
                       0, stream, inputs, h_tm1, P);
    hipLaunchKernelGGL(lstm_main_kernel, dim3(MODELS * 16), dim3(256), 0, stream,
                       c_tm1, kernel_, rkernel, bias, P, out);
}

// Round 10
// 134.902 us; speedup vs baseline: 2.0668x; 1.0554x over previous
//
#include <hip/hip_runtime.h>
#include <hip/hip_bf16.h>

#define MODELS 64
#define BATCH 64
#define IN_DIM 512
#define UNITS 512
#define NCOLS 2048
// Packed-A: per tensor [m][ks16][kq4][row64] granules of 8 bf16 (16 B)
#define GRAN_PER_TENSOR (MODELS * 16 * 4 * 64)  // 262144 granules = 4 MB/tensor

typedef __attribute__((ext_vector_type(8))) short short8;
typedef __attribute__((ext_vector_type(4))) float f32x4;

static __device__ __forceinline__ short f2bf(float f) {
    return __builtin_bit_cast(short, __float2bfloat16(f));
}
static __device__ __forceinline__ float sigmoidf_(float x) {
    return 1.0f / (1.0f + __expf(-x));
}
static __device__ __forceinline__ float tanhf_(float x) {
    float e = __expf(-2.0f * fabsf(x));
    float r = (1.0f - e) / (1.0f + e);
    return copysignf(r, x);
}

// Re-layout inputs & h_tm1 (f32) into bf16 MFMA-A-fragment order (unchanged).
__global__ __launch_bounds__(256) void prepack_A_kernel(
    const float* __restrict__ x, const float* __restrict__ h,
    short8* __restrict__ P)
{
    const int t = blockIdx.x * 256 + threadIdx.x;   // [0, 2*262144)
    const int tensor = t >> 18;
    const int r = t & (GRAN_PER_TENSOR - 1);
    const int kg = r & 3;
    const int row = (r >> 2) & 63;
    const int ks = (r >> 8) & 15;
    const int m = r >> 12;
    const float* src = (tensor ? h : x) + ((size_t)(m * 64 + row) * 512 + ks * 32 + kg * 8);
    f32x4 a0 = *(const f32x4*)src;
    f32x4 a1 = *(const f32x4*)(src + 4);
    short8 v;
    v[0] = f2bf(a0[0]); v[1] = f2bf(a0[1]); v[2] = f2bf(a0[2]); v[3] = f2bf(a0[3]);
    v[4] = f2bf(a1[0]); v[5] = f2bf(a1[1]); v[6] = f2bf(a1[2]); v[7] = f2bf(a1[3]);
    P[(size_t)tensor * GRAN_PER_TENSOR + (size_t)((m * 16 + ks) * 4 + kg) * 64 + row] = v;
}

// 512 blocks (model x 8 tiles of 64 units) x 256 threads (4 waves), 2 blocks/CU.
// Wave owns 16 units x ALL 4 gates -> in-register epilogue, no z-exchange.
// Stage [32k][4g x 64u] f32 = 32 KB/step, dbuf 64 KB. Per k-row: 4 x 256 B chunks;
// each stage wave-instr covers 1 row = 4 contiguous 256 B segments (1 KB).
__global__ __launch_bounds__(256, 2) void lstm_main_kernel(
    const float* __restrict__ c_tm1,
    const float* __restrict__ kernel_,
    const float* __restrict__ rkernel,
    const float* __restrict__ bias,
    const short8* __restrict__ Pa,
    float* __restrict__ out)
{
    __shared__ float lds[16384];  // 64 KB: 2 stage bufs x 8192 f32

    const int bid = blockIdx.x;
    const int m = bid >> 3;
    const int u0 = (bid & 7) * 64;

    const int tid = threadIdx.x;
    const int w = tid >> 6;          // wave 0..3
    const int lane = tid & 63;
    const int col16 = lane & 15;
    const int kq = lane >> 4;
    const int ucol = u0 + w * 16 + col16;   // unit column this lane owns

    const float* wbase[2] = { kernel_ + (size_t)m * IN_DIM * NCOLS,
                              rkernel + (size_t)m * UNITS * NCOLS };
    const short8* pabase[2] = { Pa + (size_t)m * 4096,
                                Pa + GRAN_PER_TENSOR + (size_t)m * 4096 };

    // stage source offsets (f32, within a 32-row K-step): j = 0..7, row = j*4 + w.
    // storage granule q=lane holds source granule lane ^ (((row>>3)&1)<<2)  (involution)
    int soff[8];
#pragma unroll
    for (int j = 0; j < 8; ++j) {
        const int row = j * 4 + w;
        const int q = lane ^ ((((row >> 3) & 1)) << 2);
        const int g = q >> 4;        // gate
        const int cq = q & 15;       // 16B-granule within 256 B chunk
        soff[j] = row * NCOLS + g * 512 + u0 + cq * 4;
    }

    f32x4 acc[4][4];                 // [batch-tile][gate]
#pragma unroll
    for (int bt = 0; bt < 4; ++bt)
#pragma unroll
        for (int g = 0; g < 4; ++g) acc[bt][g] = (f32x4){0.f, 0.f, 0.f, 0.f};

    auto STAGE = [&](int step, int bufsel) {
        const float* wb = wbase[step >> 4] + (size_t)(step & 15) * 32 * NCOLS;
#pragma unroll
        for (int j = 0; j < 8; ++j) {
            const float* src = wb + soff[j];
            float* dst = lds + bufsel * 8192 + j * 1024 + w * 256;  // wave-uniform
            __builtin_amdgcn_global_load_lds(
                (const __attribute__((address_space(1))) void*)src,
                (__attribute__((address_space(3))) void*)dst, 16, 0, 0);
        }
    };
    auto LOADA = [&](int step, short8 (&af)[4]) {
        const short8* pb = pabase[step >> 4] + (size_t)((step & 15) * 4 + kq) * 64 + col16;
#pragma unroll
        for (int bt = 0; bt < 4; ++bt)
            asm volatile("global_load_dwordx4 %0, %1, off"
                         : "=v"(af[bt]) : "v"(pb + bt * 16) : "memory");
    };
    // B-frag read: col = g*64 + w*16 + col16, rows kq*8+i; swizzle key (kq&1)<<4 -> 2-way max
    auto COMPUTE = [&](int bufsel, short8 (&af)[4]) {
        const float* lb = lds + bufsel * 8192 + kq * 8 * 256;
        const int cb = w * 16 + col16;
#pragma unroll
        for (int g = 0; g < 4; ++g) {
            const int rd = (g * 64 + cb) ^ ((kq & 1) << 4);
            short8 bfr;
#pragma unroll
            for (int i = 0; i < 8; ++i) bfr[i] = f2bf(lb[rd + i * 256]);
#pragma unroll
            for (int bt = 0; bt < 4; ++bt)
                acc[bt][g] = __builtin_amdgcn_mfma_f32_16x16x32_bf16(
                    af[bt], bfr, acc[bt][g], 0, 0, 0);
        }
    };

#define WAITV(N, af)                                                         \
    asm volatile("s_waitcnt vmcnt(" #N ")"                                   \
                 : "+v"(af[0]), "+v"(af[1]), "+v"(af[2]), "+v"(af[3])        \
                 :: "memory")
#define BAR() asm volatile("s_barrier" ::: "memory")
#define LGKM0() asm volatile("s_waitcnt lgkmcnt(0)" ::: "memory")

    short8 afA[4], afB[4];
    STAGE(0, 0);
    LOADA(0, afA);

    for (int sp = 0; sp < 16; ++sp) {
        const int te = 2 * sp;
        // step te: prefetch te+1 -> buf1/afB; compute buf0/afA
        STAGE(te + 1, 1);
        LOADA(te + 1, afB);
        WAITV(12, afA); BAR();
        COMPUTE(0, afA);
        LGKM0(); BAR();
        // step te+1: prefetch te+2 -> buf0/afA; compute buf1/afB
        if (sp < 15) {
            STAGE(te + 2, 0);
            LOADA(te + 2, afA);
            WAITV(12, afB);
        } else {
            WAITV(0, afB);
        }
        BAR();
        COMPUTE(1, afB);
        LGKM0(); BAR();
    }

    // ---- fused gate epilogue, fully in-register (wave holds all 4 gates) ----
    const float* bp = bias + (size_t)m * NCOLS;
    const float bi = bp[0 * 512 + ucol];
    const float bff = bp[1 * 512 + ucol];
    const float bcc = bp[2 * 512 + ucol];
    const float bo = bp[3 * 512 + ucol];

    const size_t mbase = (size_t)m * (BATCH * UNITS);
    const float* cprev = c_tm1 + mbase;
    float* hout0 = out;
    float* hout1 = out + (size_t)MODELS * BATCH * UNITS;
    float* cout = out + 2 * (size_t)MODELS * BATCH * UNITS;

#pragma unroll
    for (int bt = 0; bt < 4; ++bt) {
#pragma unroll
        for (int r = 0; r < 4; ++r) {
            const int b = bt * 16 + kq * 4 + r;   // batch row (D layout)
            const float z0 = acc[bt][0][r] + bi;
            const float z1 = acc[bt][1][r] + bff;
            const float z2 = acc[bt][2][r] + bcc;
            const float z3 = acc[bt][3][r] + bo;
            const float ig = sigmoidf_(z0);
            const float fg = sigmoidf_(z1);
            const float cand = tanhf_(z2);
            const float og = sigmoidf_(z3);
            const size_t idx = (size_t)b * UNITS + ucol;
            const float c = fg * cprev[idx] + ig * cand;
            const float hh = og * tanhf_(c);
            hout0[mbase + idx] = hh;
            hout1[mbase + idx] = hh;
            cout[mbase + idx] = c;
        }
    }
}

extern "C" void kernel_launch(void* const* d_in, const int* in_sizes, int n_in,
                              void* d_out, int out_size, void* d_ws, size_t ws_size,
                              hipStream_t stream) {
    const float* inputs = (const float*)d_in[0];
    const float* h_tm1 = (const float*)d_in[1];
    const float* c_tm1 = (const float*)d_in[2];
    const float* kernel_ = (const float*)d_in[3];
    const float* rkernel = (const float*)d_in[4];
    const float* bias = (const float*)d_in[5];
    float* out = (float*)d_out;

    short8* P = (short8*)d_ws;  // 8 MB of scratch
    hipLaunchKernelGGL(prepack_A_kernel, dim3(2 * GRAN_PER_TENSOR / 256), dim3(256),
                       0, stream, inputs, h_tm1, P);
    hipLaunchKernelGGL(lstm_main_kernel, dim3(MODELS * 8), dim3(256), 0, stream,
                       c_tm1, kernel_, rkernel, bias, P, out);
}